// Round 1
// baseline (222.446 us; speedup 1.0000x reference)
//
#include <hip/hip_runtime.h>

// YOLO loss: S=14, B=2, C=20, N_CH=30, batch=4096
// pred, target: (4096, 14, 14, 30) float32. Output: scalar float32.

#define SDIM 14
#define NCH  30
#define BATCH 4096
#define NCELLS (BATCH * SDIM * SDIM)   // 802816
#define L_COORD 5.0f
#define L_NOOBJ 0.5f

__global__ __launch_bounds__(256) void yolo_loss_kernel(
    const float* __restrict__ pred,
    const float* __restrict__ tgt,
    float* __restrict__ out)
{
    int cell = blockIdx.x * blockDim.x + threadIdx.x;
    float loss = 0.0f;

    if (cell < NCELLS) {
        // Each cell: 30 floats = 120 bytes, 8-byte aligned -> float2 loads.
        const float2* p2 = (const float2*)(pred + (size_t)cell * NCH);
        const float2* t2 = (const float2*)(tgt  + (size_t)cell * NCH);
        float pv[NCH], tv[NCH];
        #pragma unroll
        for (int i = 0; i < NCH / 2; ++i) {
            float2 a = p2[i];
            float2 b = t2[i];
            pv[2*i]   = a.x; pv[2*i+1] = a.y;
            tv[2*i]   = b.x; tv[2*i+1] = b.y;
        }

        const float invS = 1.0f / (float)SDIM;
        float m  = (tv[4] > 0.0f) ? 1.0f : 0.0f;
        float nm = 1.0f - m;

        // target box 0 -> xyxy
        float tcx = tv[0] * invS, tcy = tv[1] * invS;
        float tw  = tv[2],        th  = tv[3];
        float tx1 = tcx - 0.5f * tw, ty1 = tcy - 0.5f * th;
        float tx2 = tcx + 0.5f * tw, ty2 = tcy + 0.5f * th;
        float ta  = (tx2 - tx1) * (ty2 - ty1);

        // IoU of each pred box vs target box 0
        float iou[2];
        #pragma unroll
        for (int b = 0; b < 2; ++b) {
            float cx = pv[5*b + 0] * invS, cy = pv[5*b + 1] * invS;
            float w  = pv[5*b + 2],        h  = pv[5*b + 3];
            float x1 = cx - 0.5f * w, y1 = cy - 0.5f * h;
            float x2 = cx + 0.5f * w, y2 = cy + 0.5f * h;
            float lx = fmaxf(x1, tx1), ly = fmaxf(y1, ty1);
            float rx = fminf(x2, tx2), ry = fminf(y2, ty2);
            float iw = fmaxf(rx - lx, 0.0f);
            float ih = fmaxf(ry - ly, 0.0f);
            float inter = iw * ih;
            float pa = (x2 - x1) * (y2 - y1);
            iou[b] = inter / (pa + ta - inter);
        }

        // argmax (first-wins on ties, matching jnp.argmax)
        int   idx     = (iou[1] > iou[0]) ? 1 : 0;
        float max_iou = idx ? iou[1] : iou[0];
        int   o       = 5 * idx;

        float dxy = (pv[o+0] - tv[o+0]) * (pv[o+0] - tv[o+0])
                  + (pv[o+1] - tv[o+1]) * (pv[o+1] - tv[o+1]);
        float sw  = sqrtf(pv[o+2]) - sqrtf(tv[o+2]);
        float sh  = sqrtf(pv[o+3]) - sqrtf(tv[o+3]);
        float dwh = sw * sw + sh * sh;
        float dob = (pv[o+4] - max_iou) * (pv[o+4] - max_iou);

        float dcls = 0.0f;
        #pragma unroll
        for (int c = 10; c < NCH; ++c) {
            float d = pv[c] - tv[c];
            dcls += d * d;
        }

        float d4 = pv[4] - tv[4];
        float d9 = pv[9] - tv[9];
        float dnoobj = d4 * d4 + d9 * d9;

        loss = m * (L_COORD * (dxy + dwh) + dob + dcls) + nm * L_NOOBJ * dnoobj;
    }

    // wave-level reduction (wave = 64 lanes)
    #pragma unroll
    for (int off = 32; off > 0; off >>= 1)
        loss += __shfl_down(loss, off, 64);

    __shared__ float wsum[4];
    int lane = threadIdx.x & 63;
    int wid  = threadIdx.x >> 6;
    if (lane == 0) wsum[wid] = loss;
    __syncthreads();
    if (threadIdx.x == 0) {
        float s = wsum[0] + wsum[1] + wsum[2] + wsum[3];
        atomicAdd(out, s * (1.0f / (float)BATCH));
    }
}

extern "C" void kernel_launch(void* const* d_in, const int* in_sizes, int n_in,
                              void* d_out, int out_size, void* d_ws, size_t ws_size,
                              hipStream_t stream)
{
    const float* pred = (const float*)d_in[0];
    const float* tgt  = (const float*)d_in[1];
    float* out        = (float*)d_out;

    // d_out is re-poisoned to 0xAA before every timed launch -> zero it (capture-safe).
    hipMemsetAsync(out, 0, sizeof(float), stream);

    dim3 block(256);
    dim3 grid((NCELLS + 255) / 256);
    hipLaunchKernelGGL(yolo_loss_kernel, grid, block, 0, stream, pred, tgt, out);
}

// Round 2
// 215.450 us; speedup vs baseline: 1.0325x; 1.0325x over previous
//
#include <hip/hip_runtime.h>

// YOLO loss: S=14, B=2, C=20, N_CH=30, batch=4096
// pred, target: (4096, 14, 14, 30) float32. Output: scalar float32.
//
// R1: LDS-staged transpose. Coalesced float4 global->LDS, then per-cell
// register copy from LDS. Two phases reuse one 30 KiB buffer (5 blocks/CU).

#define SDIM 14
#define NCH  30
#define BATCH 4096
#define NCELLS (BATCH * SDIM * SDIM)   // 802816
#define L_COORD 5.0f
#define L_NOOBJ 0.5f

#define TILE_CELLS 256
#define TILE_FLOATS (TILE_CELLS * NCH)   // 7680 floats = 30720 B
#define TILE_F4     (TILE_FLOATS / 4)    // 1920

__global__ __launch_bounds__(256) void yolo_loss_kernel(
    const float* __restrict__ pred,
    const float* __restrict__ tgt,
    float* __restrict__ out)
{
    __shared__ float tile[TILE_FLOATS];

    const int tid = threadIdx.x;
    const size_t cell0 = (size_t)blockIdx.x * TILE_CELLS;

    // ---- Phase A: stage pred tile (coalesced float4), copy own cell to regs
    {
        const float4* gp = (const float4*)(pred + cell0 * NCH);
        float4* lt = (float4*)tile;
        #pragma unroll
        for (int k = 0; k < 8; ++k) {
            int idx = tid + k * 256;
            if (idx < TILE_F4) lt[idx] = gp[idx];
        }
    }
    __syncthreads();

    float pv[NCH];
    {
        const float2* lp = (const float2*)(tile + tid * NCH);
        #pragma unroll
        for (int i = 0; i < NCH / 2; ++i) {
            float2 v = lp[i];
            pv[2*i] = v.x; pv[2*i+1] = v.y;
        }
    }
    __syncthreads();

    // ---- Phase B: stage tgt tile into the same buffer
    {
        const float4* gt = (const float4*)(tgt + cell0 * NCH);
        float4* lt = (float4*)tile;
        #pragma unroll
        for (int k = 0; k < 8; ++k) {
            int idx = tid + k * 256;
            if (idx < TILE_F4) lt[idx] = gt[idx];
        }
    }
    __syncthreads();

    float tv[NCH];
    {
        const float2* lp = (const float2*)(tile + tid * NCH);
        #pragma unroll
        for (int i = 0; i < NCH / 2; ++i) {
            float2 v = lp[i];
            tv[2*i] = v.x; tv[2*i+1] = v.y;
        }
    }

    // ---- Per-cell loss math (all cells valid: 802816 = 3136*256)
    const float invS = 1.0f / (float)SDIM;
    float m  = (tv[4] > 0.0f) ? 1.0f : 0.0f;
    float nm = 1.0f - m;

    // target box 0 -> xyxy
    float tcx = tv[0] * invS, tcy = tv[1] * invS;
    float tw  = tv[2],        th  = tv[3];
    float tx1 = tcx - 0.5f * tw, ty1 = tcy - 0.5f * th;
    float tx2 = tcx + 0.5f * tw, ty2 = tcy + 0.5f * th;
    float ta  = (tx2 - tx1) * (ty2 - ty1);

    float iou[2];
    #pragma unroll
    for (int b = 0; b < 2; ++b) {
        float cx = pv[5*b + 0] * invS, cy = pv[5*b + 1] * invS;
        float w  = pv[5*b + 2],        h  = pv[5*b + 3];
        float x1 = cx - 0.5f * w, y1 = cy - 0.5f * h;
        float x2 = cx + 0.5f * w, y2 = cy + 0.5f * h;
        float lx = fmaxf(x1, tx1), ly = fmaxf(y1, ty1);
        float rx = fminf(x2, tx2), ry = fminf(y2, ty2);
        float iw = fmaxf(rx - lx, 0.0f);
        float ih = fmaxf(ry - ly, 0.0f);
        float inter = iw * ih;
        float pa = (x2 - x1) * (y2 - y1);
        iou[b] = inter / (pa + ta - inter);
    }

    // argmax (first-wins on ties, matching jnp.argmax)
    int   idx     = (iou[1] > iou[0]) ? 1 : 0;
    float max_iou = idx ? iou[1] : iou[0];
    int   o       = 5 * idx;

    float dxy = (pv[o+0] - tv[o+0]) * (pv[o+0] - tv[o+0])
              + (pv[o+1] - tv[o+1]) * (pv[o+1] - tv[o+1]);
    float sw  = sqrtf(pv[o+2]) - sqrtf(tv[o+2]);
    float sh  = sqrtf(pv[o+3]) - sqrtf(tv[o+3]);
    float dwh = sw * sw + sh * sh;
    float dob = (pv[o+4] - max_iou) * (pv[o+4] - max_iou);

    float dcls = 0.0f;
    #pragma unroll
    for (int c = 10; c < NCH; ++c) {
        float d = pv[c] - tv[c];
        dcls += d * d;
    }

    float d4 = pv[4] - tv[4];
    float d9 = pv[9] - tv[9];
    float dnoobj = d4 * d4 + d9 * d9;

    float loss = m * (L_COORD * (dxy + dwh) + dob + dcls) + nm * L_NOOBJ * dnoobj;

    // ---- Reduction: wave shuffle (64) -> LDS -> one atomic per block
    #pragma unroll
    for (int off = 32; off > 0; off >>= 1)
        loss += __shfl_down(loss, off, 64);

    __shared__ float wsum[4];
    int lane = tid & 63;
    int wid  = tid >> 6;
    if (lane == 0) wsum[wid] = loss;
    __syncthreads();
    if (tid == 0) {
        float s = wsum[0] + wsum[1] + wsum[2] + wsum[3];
        atomicAdd(out, s * (1.0f / (float)BATCH));
    }
}

extern "C" void kernel_launch(void* const* d_in, const int* in_sizes, int n_in,
                              void* d_out, int out_size, void* d_ws, size_t ws_size,
                              hipStream_t stream)
{
    const float* pred = (const float*)d_in[0];
    const float* tgt  = (const float*)d_in[1];
    float* out        = (float*)d_out;

    // d_out is re-poisoned to 0xAA before every timed launch -> zero it (capture-safe).
    hipMemsetAsync(out, 0, sizeof(float), stream);

    dim3 block(256);
    dim3 grid(NCELLS / TILE_CELLS);   // 3136, exact
    hipLaunchKernelGGL(yolo_loss_kernel, grid, block, 0, stream, pred, tgt, out);
}

// Round 3
// 214.423 us; speedup vs baseline: 1.0374x; 1.0048x over previous
//
#include <hip/hip_runtime.h>

// YOLO loss: S=14, B=2, C=20, N_CH=30, batch=4096
// pred, target: (4096, 14, 14, 30) float32. Output: scalar float32.
//
// R2: kill the same-address atomicAdd serializer (3136 atomics ~= 80-90us
// floor in R0/R1). Two-stage reduction via d_ws. Keep R1's coalesced
// float4 -> LDS -> per-cell register path.

#define SDIM 14
#define NCH  30
#define BATCH 4096
#define NCELLS (BATCH * SDIM * SDIM)   // 802816
#define NBLOCKS (NCELLS / 256)         // 3136
#define L_COORD 5.0f
#define L_NOOBJ 0.5f

#define TILE_CELLS 256
#define TILE_FLOATS (TILE_CELLS * NCH)   // 7680 floats = 30720 B
#define TILE_F4     (TILE_FLOATS / 4)    // 1920

__global__ __launch_bounds__(256) void yolo_loss_stage1(
    const float* __restrict__ pred,
    const float* __restrict__ tgt,
    float* __restrict__ partial)
{
    __shared__ float tile[TILE_FLOATS];

    const int tid = threadIdx.x;
    const size_t cell0 = (size_t)blockIdx.x * TILE_CELLS;

    // ---- Phase A: stage pred tile (coalesced float4), copy own cell to regs
    {
        const float4* gp = (const float4*)(pred + cell0 * NCH);
        float4* lt = (float4*)tile;
        #pragma unroll
        for (int k = 0; k < 8; ++k) {
            int idx = tid + k * 256;
            if (idx < TILE_F4) lt[idx] = gp[idx];
        }
    }
    __syncthreads();

    float pv[NCH];
    {
        const float2* lp = (const float2*)(tile + tid * NCH);
        #pragma unroll
        for (int i = 0; i < NCH / 2; ++i) {
            float2 v = lp[i];
            pv[2*i] = v.x; pv[2*i+1] = v.y;
        }
    }
    __syncthreads();

    // ---- Phase B: stage tgt tile into the same buffer
    {
        const float4* gt = (const float4*)(tgt + cell0 * NCH);
        float4* lt = (float4*)tile;
        #pragma unroll
        for (int k = 0; k < 8; ++k) {
            int idx = tid + k * 256;
            if (idx < TILE_F4) lt[idx] = gt[idx];
        }
    }
    __syncthreads();

    float tv[NCH];
    {
        const float2* lp = (const float2*)(tile + tid * NCH);
        #pragma unroll
        for (int i = 0; i < NCH / 2; ++i) {
            float2 v = lp[i];
            tv[2*i] = v.x; tv[2*i+1] = v.y;
        }
    }

    // ---- Per-cell loss math (all cells valid: 802816 = 3136*256)
    const float invS = 1.0f / (float)SDIM;
    float m  = (tv[4] > 0.0f) ? 1.0f : 0.0f;
    float nm = 1.0f - m;

    // target box 0 -> xyxy
    float tcx = tv[0] * invS, tcy = tv[1] * invS;
    float tw  = tv[2],        th  = tv[3];
    float tx1 = tcx - 0.5f * tw, ty1 = tcy - 0.5f * th;
    float tx2 = tcx + 0.5f * tw, ty2 = tcy + 0.5f * th;
    float ta  = (tx2 - tx1) * (ty2 - ty1);

    float iou[2];
    #pragma unroll
    for (int b = 0; b < 2; ++b) {
        float cx = pv[5*b + 0] * invS, cy = pv[5*b + 1] * invS;
        float w  = pv[5*b + 2],        h  = pv[5*b + 3];
        float x1 = cx - 0.5f * w, y1 = cy - 0.5f * h;
        float x2 = cx + 0.5f * w, y2 = cy + 0.5f * h;
        float lx = fmaxf(x1, tx1), ly = fmaxf(y1, ty1);
        float rx = fminf(x2, tx2), ry = fminf(y2, ty2);
        float iw = fmaxf(rx - lx, 0.0f);
        float ih = fmaxf(ry - ly, 0.0f);
        float inter = iw * ih;
        float pa = (x2 - x1) * (y2 - y1);
        iou[b] = inter / (pa + ta - inter);
    }

    // argmax (first-wins on ties, matching jnp.argmax)
    int   idx     = (iou[1] > iou[0]) ? 1 : 0;
    float max_iou = idx ? iou[1] : iou[0];
    int   o       = 5 * idx;

    float dxy = (pv[o+0] - tv[o+0]) * (pv[o+0] - tv[o+0])
              + (pv[o+1] - tv[o+1]) * (pv[o+1] - tv[o+1]);
    float sw  = sqrtf(pv[o+2]) - sqrtf(tv[o+2]);
    float sh  = sqrtf(pv[o+3]) - sqrtf(tv[o+3]);
    float dwh = sw * sw + sh * sh;
    float dob = (pv[o+4] - max_iou) * (pv[o+4] - max_iou);

    float dcls = 0.0f;
    #pragma unroll
    for (int c = 10; c < NCH; ++c) {
        float d = pv[c] - tv[c];
        dcls += d * d;
    }

    float d4 = pv[4] - tv[4];
    float d9 = pv[9] - tv[9];
    float dnoobj = d4 * d4 + d9 * d9;

    float loss = m * (L_COORD * (dxy + dwh) + dob + dcls) + nm * L_NOOBJ * dnoobj;

    // ---- Reduction: wave shuffle (64) -> LDS -> one partial per block (no atomics)
    #pragma unroll
    for (int off = 32; off > 0; off >>= 1)
        loss += __shfl_down(loss, off, 64);

    __shared__ float wsum[4];
    int lane = tid & 63;
    int wid  = tid >> 6;
    if (lane == 0) wsum[wid] = loss;
    __syncthreads();
    if (tid == 0) {
        partial[blockIdx.x] = wsum[0] + wsum[1] + wsum[2] + wsum[3];
    }
}

__global__ __launch_bounds__(256) void yolo_loss_stage2(
    const float* __restrict__ partial,
    float* __restrict__ out)
{
    const int tid = threadIdx.x;
    float s = 0.0f;
    for (int i = tid; i < NBLOCKS; i += 256) s += partial[i];

    #pragma unroll
    for (int off = 32; off > 0; off >>= 1)
        s += __shfl_down(s, off, 64);

    __shared__ float wsum[4];
    int lane = tid & 63;
    int wid  = tid >> 6;
    if (lane == 0) wsum[wid] = s;
    __syncthreads();
    if (tid == 0) {
        out[0] = (wsum[0] + wsum[1] + wsum[2] + wsum[3]) * (1.0f / (float)BATCH);
    }
}

extern "C" void kernel_launch(void* const* d_in, const int* in_sizes, int n_in,
                              void* d_out, int out_size, void* d_ws, size_t ws_size,
                              hipStream_t stream)
{
    const float* pred = (const float*)d_in[0];
    const float* tgt  = (const float*)d_in[1];
    float* out        = (float*)d_out;
    float* partial    = (float*)d_ws;   // 3136 floats = 12.5 KB

    hipLaunchKernelGGL(yolo_loss_stage1, dim3(NBLOCKS), dim3(256), 0, stream,
                       pred, tgt, partial);
    hipLaunchKernelGGL(yolo_loss_stage2, dim3(1), dim3(256), 0, stream,
                       partial, out);
}